// Round 1
// baseline (276.926 us; speedup 1.0000x reference)
//
#include <hip/hip_runtime.h>

// NeuralAdditiveModel: out[b] = sum_f( W3[f] . relu(W2[f]^T relu(x[b,f]*W1[f]+b1[f]) + b2[f]) + b3[f] ) + bias
// B=8192, F=128, S=128, H1=64, O=1
#define B_ 8192
#define F_ 128
#define S_ 128
#define H_ 64

// Initialize out[b] = bias[0]; main kernel atomically accumulates per-feature outputs.
__global__ __launch_bounds__(256) void nam_init(float* __restrict__ out,
                                                const float* __restrict__ bias) {
    int i = blockIdx.x * 256 + threadIdx.x;
    if (i < B_) out[i] = bias[0];
}

// One thread = one (b, f) pair. f is block-uniform so all weight accesses are
// wave-uniform -> compiler emits scalar (s_load) reads; inner loop is
// v_fmac_f32 acc[h], sW2, vH1 (64 independent FMA chains per thread).
__global__ __launch_bounds__(256) void nam_main(
    const float* __restrict__ x,   // [B,F]
    const float* __restrict__ W1,  // [F,S]
    const float* __restrict__ b1,  // [F,S]
    const float* __restrict__ W2,  // [F,S,H]
    const float* __restrict__ b2,  // [F,H]
    const float* __restrict__ W3,  // [F,H] (O=1)
    const float* __restrict__ b3,  // [F]
    float* __restrict__ out)       // [B]
{
    const int nb = B_ / 256;             // 32 b-tiles per feature
    const int f  = blockIdx.x / nb;      // consecutive blocks share f -> L2/sK$ locality for W2[f]
    const int b  = (blockIdx.x % nb) * 256 + threadIdx.x;

    const float xv = x[(size_t)b * F_ + f];
    const float* __restrict__ W1f = W1 + f * S_;
    const float* __restrict__ b1f = b1 + f * S_;
    const float* __restrict__ W2f = W2 + (size_t)f * S_ * H_;

    float acc[H_];
#pragma unroll
    for (int h = 0; h < H_; ++h) acc[h] = 0.f;

    for (int s = 0; s < S_; ++s) {
        const float h1 = fmaxf(fmaf(xv, W1f[s], b1f[s]), 0.f);  // relu(x*W1+b1), scalar W1/b1
        const float* __restrict__ w2 = W2f + s * H_;
#pragma unroll
        for (int h = 0; h < H_; ++h) acc[h] = fmaf(h1, w2[h], acc[h]);
    }

    const float* __restrict__ b2f = b2 + f * H_;
    const float* __restrict__ W3f = W3 + f * H_;
    float fo = b3[f];
#pragma unroll
    for (int h = 0; h < H_; ++h)
        fo = fmaf(fmaxf(acc[h] + b2f[h], 0.f), W3f[h], fo);  // relu(h2)·W3 + b3

    atomicAdd(&out[b], fo);  // 128 adds per out[b], device-scope, negligible contention
}

extern "C" void kernel_launch(void* const* d_in, const int* in_sizes, int n_in,
                              void* d_out, int out_size, void* d_ws, size_t ws_size,
                              hipStream_t stream) {
    const float* x    = (const float*)d_in[0];
    const float* W1   = (const float*)d_in[1];
    const float* b1   = (const float*)d_in[2];
    const float* W2   = (const float*)d_in[3];
    const float* b2   = (const float*)d_in[4];
    const float* W3   = (const float*)d_in[5];
    const float* b3   = (const float*)d_in[6];
    const float* bias = (const float*)d_in[7];
    float* out = (float*)d_out;

    nam_init<<<(B_ + 255) / 256, 256, 0, stream>>>(out, bias);
    nam_main<<<F_ * (B_ / 256), 256, 0, stream>>>(x, W1, b1, W2, b2, W3, b3, out);
}

// Round 4
// 121.194 us; speedup vs baseline: 2.2850x; 2.2850x over previous
//
#include <hip/hip_runtime.h>
#include <hip/hip_bf16.h>

// NeuralAdditiveModel: out[b] = sum_f( W3[f] . relu(W2[f]^T relu(x[b,f]*W1[f]+b1[f]) + b2[f]) + b3[f] ) + bias
// B=8192, F=128, S=128, H1=64, O=1
#define B_ 8192
#define F_ 128
#define S_ 128
#define H_ 64

typedef __attribute__((ext_vector_type(4))) float f32x4;
typedef __attribute__((ext_vector_type(8))) short bf16x8;  // 8 bf16 in 4 VGPRs

__global__ __launch_bounds__(256) void nam_init(float* __restrict__ out,
                                                const float* __restrict__ bias) {
    int i = blockIdx.x * 256 + threadIdx.x;
    if (i < B_) out[i] = bias[0];
}

static __device__ __forceinline__ short f2bf(float v) {
    __hip_bfloat16 t = __float2bfloat16(v);   // RNE; compiler pairs into v_cvt_pk_bf16_f32
    return __builtin_bit_cast(short, t);
}

// One block: feature f x 256 batch rows. 4 waves, each: 64 b-cols x 64 h x K=128.
// GEMM computed operand-swapped: h2^T = W2^T(MxK=64x128) * h1^T(KxN=128x64) so the
// MFMA C layout (col = lane&15 = batch, row = h) keeps the epilogue h-reduction
// mostly lane-local.
__global__ __launch_bounds__(256) void nam_mfma(
    const float* __restrict__ x,   // [B,F]
    const float* __restrict__ W1,  // [F,S]
    const float* __restrict__ b1,  // [F,S]
    const float* __restrict__ W2,  // [F,S,H]
    const float* __restrict__ b2,  // [F,H]
    const float* __restrict__ W3,  // [F,H] (O=1)
    const float* __restrict__ b3,  // [F]
    float* __restrict__ out)       // [B]
{
    const int f   = blockIdx.x >> 5;        // 32 consecutive blocks share f (weight locality)
    const int bt  = blockIdx.x & 31;
    const int tid = threadIdx.x;
    const int w   = tid >> 6;
    const int l   = tid & 63;
    const int l16 = l & 15;
    const int lg  = l >> 4;                 // lane group 0..3

    const int bbase = bt * 256 + w * 64;    // this wave's 64 batch rows

    const float* __restrict__ W1f = W1 + f * S_;
    const float* __restrict__ b1f = b1 + f * S_;
    const float* __restrict__ W2f = W2 + (size_t)f * S_ * H_;

    // x for the 4 batch n-tiles (16-way broadcast within lane groups)
    float xv[4];
#pragma unroll
    for (int n = 0; n < 4; ++n)
        xv[n] = x[(size_t)(bbase + n * 16 + l16) * F_ + f];

    f32x4 acc[4][4];                        // [m = h-tile][n = b-tile]
#pragma unroll
    for (int m = 0; m < 4; ++m)
#pragma unroll
        for (int n = 0; n < 4; ++n)
            acc[m][n] = (f32x4){0.f, 0.f, 0.f, 0.f};

    for (int kk = 0; kk < 4; ++kk) {
        const int s0 = kk * 32 + lg * 8;    // this lane's 8 consecutive s values

        // W1/b1 octets (same address within a lane group -> broadcast)
        const f32x4 w1a = *(const f32x4*)(W1f + s0);
        const f32x4 w1b = *(const f32x4*)(W1f + s0 + 4);
        const f32x4 b1a = *(const f32x4*)(b1f + s0);
        const f32x4 b1b = *(const f32x4*)(b1f + s0 + 4);

        // B-frags: h1^T[k = s][col = b] = relu(x[b]*W1[s]+b1[s]), bf16
        bf16x8 bfrag[4];
#pragma unroll
        for (int n = 0; n < 4; ++n) {
#pragma unroll
            for (int j = 0; j < 4; ++j) {
                bfrag[n][j]     = f2bf(fmaxf(fmaf(xv[n], w1a[j], b1a[j]), 0.f));
                bfrag[n][j + 4] = f2bf(fmaxf(fmaf(xv[n], w1b[j], b1b[j]), 0.f));
            }
        }

        // A-frags: W2^T[row = h][k = s] = W2[s][h], bf16 (imm-offset dword loads)
        bf16x8 afrag[4];
        const float* __restrict__ w2p = W2f + (size_t)s0 * H_ + l16;
#pragma unroll
        for (int m = 0; m < 4; ++m) {
#pragma unroll
            for (int j = 0; j < 8; ++j)
                afrag[m][j] = f2bf(w2p[j * H_ + m * 16]);
        }

#pragma unroll
        for (int m = 0; m < 4; ++m)
#pragma unroll
            for (int n = 0; n < 4; ++n)
                acc[m][n] = __builtin_amdgcn_mfma_f32_16x16x32_bf16(
                    afrag[m], bfrag[n], acc[m][n], 0, 0, 0);
    }

    // Epilogue: fo[b] = sum_h relu(h2[b][h] + b2[h]) * W3[h]  (+ b3 once per (b,f))
    // Lane holds h = m*16 + lg*4 + r for its b-col; b2/W3 stay fp32.
    const float* __restrict__ b2f = b2 + f * H_;
    const float* __restrict__ W3f = W3 + f * H_;
    f32x4 b2v[4], w3v[4];
#pragma unroll
    for (int m = 0; m < 4; ++m) {
        b2v[m] = *(const f32x4*)(b2f + m * 16 + lg * 4);
        w3v[m] = *(const f32x4*)(W3f + m * 16 + lg * 4);
    }
    const float b3f = b3[f];

#pragma unroll
    for (int n = 0; n < 4; ++n) {
        float fo = 0.f;
#pragma unroll
        for (int m = 0; m < 4; ++m)
#pragma unroll
            for (int r = 0; r < 4; ++r)
                fo = fmaf(fmaxf(acc[m][n][r] + b2v[m][r], 0.f), w3v[m][r], fo);
        // lanes l, l^16, l^32, l^48 hold disjoint h-quarters of the same b
        fo += __shfl_xor(fo, 16);
        fo += __shfl_xor(fo, 32);
        if (lg == 0)
            atomicAdd(&out[bbase + n * 16 + l16], fo + b3f);
    }
}

extern "C" void kernel_launch(void* const* d_in, const int* in_sizes, int n_in,
                              void* d_out, int out_size, void* d_ws, size_t ws_size,
                              hipStream_t stream) {
    const float* x    = (const float*)d_in[0];
    const float* W1   = (const float*)d_in[1];
    const float* b1   = (const float*)d_in[2];
    const float* W2   = (const float*)d_in[3];
    const float* b2   = (const float*)d_in[4];
    const float* W3   = (const float*)d_in[5];
    const float* b3   = (const float*)d_in[6];
    const float* bias = (const float*)d_in[7];
    float* out = (float*)d_out;

    nam_init<<<(B_ + 255) / 256, 256, 0, stream>>>(out, bias);
    nam_mfma<<<F_ * (B_ / 256), 256, 0, stream>>>(x, W1, b1, W2, b2, W3, b3, out);
}

// Round 8
// 110.359 us; speedup vs baseline: 2.5093x; 1.0982x over previous
//
#include <hip/hip_runtime.h>
#include <hip/hip_bf16.h>

// NeuralAdditiveModel: out[b] = sum_f( W3[f] . relu(W2[f]^T relu(x[b,f]*W1[f]+b1[f]) + b2[f]) + b3[f] ) + bias
// B=8192, F=128, S=128, H1=64, O=1
#define B_ 8192
#define F_ 128
#define S_ 128
#define H_ 64

typedef __attribute__((ext_vector_type(4))) float f32x4;
typedef __attribute__((ext_vector_type(8))) short bf16x8;  // 8 bf16 in 4 VGPRs

__global__ __launch_bounds__(256) void nam_init(float* __restrict__ out,
                                                const float* __restrict__ bias) {
    int i = blockIdx.x * 256 + threadIdx.x;
    if (i < B_) out[i] = bias[0];
}

static __device__ __forceinline__ short f2bf(float v) {
    __hip_bfloat16 t = __float2bfloat16(v);   // RNE
    return __builtin_bit_cast(short, t);
}

// Pre-pass: W2 [F][S][H] fp32 -> d_ws as bf16 in MFMA A-frag order [f][kk][m][lane][8].
// Lane l (l16=l&15, lg=l>>4), frag m, K-step kk needs W2^T[h=m*16+l16][s=kk*32+lg*8+j],
// i.e. W2[f][kk*32+lg*8+j][m*16+l16], j=0..7. One thread per (f,kk,m,l) = 131072 threads.
// Per (f,kk,m,lg): 16 threads read 64B-contiguous fp32; writes are fully coalesced 16B.
__global__ __launch_bounds__(256) void nam_prep(const float* __restrict__ W2,
                                                bf16x8* __restrict__ W2bf) {
    const int idx = blockIdx.x * 256 + threadIdx.x;   // [f][kk][m][l]
    const int l   = idx & 63;
    const int m   = (idx >> 6) & 3;
    const int kk  = (idx >> 8) & 3;
    const int f   = idx >> 10;
    const int l16 = l & 15, lg = l >> 4;

    const float* __restrict__ src =
        W2 + ((size_t)f * S_ + kk * 32 + lg * 8) * H_ + m * 16 + l16;
    bf16x8 v;
#pragma unroll
    for (int j = 0; j < 8; ++j) v[j] = f2bf(src[j * H_]);
    W2bf[idx] = v;
}

// One block: feature f x 256 batch rows. 4 waves, each: 64 b-cols x 64 h x K=128.
// h2^T = W2^T(64x128) * h1^T(128x64); C layout: col(lane&15)=batch, row=h.
// A-frags come pre-converted/pre-swizzled from d_ws: 1 dwordx4 per frag.
__global__ __launch_bounds__(256) void nam_mfma(
    const float* __restrict__ x,        // [B,F]
    const float* __restrict__ W1,       // [F,S]
    const float* __restrict__ b1,       // [F,S]
    const bf16x8* __restrict__ W2bf,    // [F][4][4][64] frags
    const float* __restrict__ b2,       // [F,H]
    const float* __restrict__ W3,       // [F,H] (O=1)
    const float* __restrict__ b3,       // [F]
    float* __restrict__ out)            // [B]
{
    const int f   = blockIdx.x >> 5;    // 32 consecutive blocks share f
    const int bt  = blockIdx.x & 31;
    const int tid = threadIdx.x;
    const int w   = tid >> 6;
    const int l   = tid & 63;
    const int l16 = l & 15;
    const int lg  = l >> 4;

    const int bbase = bt * 256 + w * 64;

    const float* __restrict__ W1f = W1 + f * S_;
    const float* __restrict__ b1f = b1 + f * S_;
    const bf16x8* __restrict__ W2f = W2bf + (size_t)f * 16 * 64 + l;

    float xv[4];
#pragma unroll
    for (int n = 0; n < 4; ++n)
        xv[n] = x[(size_t)(bbase + n * 16 + l16) * F_ + f];

    f32x4 acc[4][4];
#pragma unroll
    for (int m = 0; m < 4; ++m)
#pragma unroll
        for (int n = 0; n < 4; ++n)
            acc[m][n] = (f32x4){0.f, 0.f, 0.f, 0.f};

#pragma unroll
    for (int kk = 0; kk < 4; ++kk) {
        const int s0 = kk * 32 + lg * 8;

        // A-frags: 4 coalesced 16B loads (1024B/wave each), L1-resident after wave 0
        bf16x8 afrag[4];
#pragma unroll
        for (int m = 0; m < 4; ++m)
            afrag[m] = W2f[(kk * 4 + m) * 64];

        const f32x4 w1a = *(const f32x4*)(W1f + s0);
        const f32x4 w1b = *(const f32x4*)(W1f + s0 + 4);
        const f32x4 b1a = *(const f32x4*)(b1f + s0);
        const f32x4 b1b = *(const f32x4*)(b1f + s0 + 4);

        // B-frags: h1^T[k=s][col=b] = relu(x[b]*W1[s]+b1[s]) in bf16
        bf16x8 bfrag[4];
#pragma unroll
        for (int n = 0; n < 4; ++n) {
#pragma unroll
            for (int j = 0; j < 4; ++j) {
                bfrag[n][j]     = f2bf(fmaxf(fmaf(xv[n], w1a[j], b1a[j]), 0.f));
                bfrag[n][j + 4] = f2bf(fmaxf(fmaf(xv[n], w1b[j], b1b[j]), 0.f));
            }
        }

#pragma unroll
        for (int m = 0; m < 4; ++m)
#pragma unroll
            for (int n = 0; n < 4; ++n)
                acc[m][n] = __builtin_amdgcn_mfma_f32_16x16x32_bf16(
                    afrag[m], bfrag[n], acc[m][n], 0, 0, 0);
    }

    // Epilogue: fo[b] = sum_h relu(h2+b2)*W3 (+b3); lane h = m*16+lg*4+r
    const float* __restrict__ b2f = b2 + f * H_;
    const float* __restrict__ W3f = W3 + f * H_;
    f32x4 b2v[4], w3v[4];
#pragma unroll
    for (int m = 0; m < 4; ++m) {
        b2v[m] = *(const f32x4*)(b2f + m * 16 + lg * 4);
        w3v[m] = *(const f32x4*)(W3f + m * 16 + lg * 4);
    }
    const float b3f = b3[f];

#pragma unroll
    for (int n = 0; n < 4; ++n) {
        float fo = 0.f;
#pragma unroll
        for (int m = 0; m < 4; ++m)
#pragma unroll
            for (int r = 0; r < 4; ++r)
                fo = fmaf(fmaxf(acc[m][n][r] + b2v[m][r], 0.f), w3v[m][r], fo);
        fo += __shfl_xor(fo, 16);
        fo += __shfl_xor(fo, 32);
        if (lg == 0)
            atomicAdd(&out[bbase + n * 16 + l16], fo + b3f);
    }
}

extern "C" void kernel_launch(void* const* d_in, const int* in_sizes, int n_in,
                              void* d_out, int out_size, void* d_ws, size_t ws_size,
                              hipStream_t stream) {
    const float* x    = (const float*)d_in[0];
    const float* W1   = (const float*)d_in[1];
    const float* b1   = (const float*)d_in[2];
    const float* W2   = (const float*)d_in[3];
    const float* b2   = (const float*)d_in[4];
    const float* W3   = (const float*)d_in[5];
    const float* b3   = (const float*)d_in[6];
    const float* bias = (const float*)d_in[7];
    float* out = (float*)d_out;
    bf16x8* W2bf = (bf16x8*)d_ws;       // 2 MB: [F][4][4][64] x 16B frags

    nam_init<<<(B_ + 255) / 256, 256, 0, stream>>>(out, bias);
    nam_prep<<<(F_ * 16 * 64) / 256, 256, 0, stream>>>(W2, W2bf);
    nam_mfma<<<F_ * (B_ / 256), 256, 0, stream>>>(x, W1, b1, W2bf, b2, W3, b3, out);
}